// Round 14
// baseline (214.462 us; speedup 1.0000x reference)
//
#include <hip/hip_runtime.h>
#include <hip/hip_bf16.h>
#include <stdint.h>

typedef __hip_bfloat16 bf16;
typedef unsigned long long u64;
typedef __attribute__((ext_vector_type(4))) float f32x4;
typedef __attribute__((ext_vector_type(8))) short short8;

#define MFMA16 __builtin_amdgcn_mfma_f32_16x16x32_bf16

constexpr int Bc = 2, Nc = 2048, Ec = 1024, Hc = 16, Dc = 64;
constexpr int Mc = Bc * Nc;   // 4096 tokens
constexpr int Kc = Ec;        // 1024 inner dim

// ---- ws layout (bytes) ----
constexpr size_t OFF_XB   = 256;
constexpr size_t SZ_XE    = (size_t)Mc * Ec * 2;   // 8 MB (M x E bf16)
constexpr size_t SZ_W     = (size_t)Ec * Ec * 2;   // 2 MB
constexpr size_t OFF_WQB  = OFF_XB  + SZ_XE;
constexpr size_t OFF_WKB  = OFF_WQB + SZ_W;
constexpr size_t OFF_WVB  = OFF_WKB + SZ_W;
constexpr size_t OFF_WOB  = OFF_WVB + SZ_W;
constexpr size_t OFF_QB   = OFF_WOB + SZ_W;
constexpr size_t OFF_KB   = OFF_QB  + SZ_XE;
constexpr size_t OFF_VTB  = OFF_KB  + SZ_XE;       // V transposed (B,H,D,N)
constexpr size_t OFF_OB   = OFF_VTB + SZ_XE;
constexpr size_t OFF_MP   = OFF_OB  + SZ_XE;       // packed mask: 131072 u64 = 1 MB

// Q prescale: 1/sqrt(D) folded with log2(e) so scores are already in exp2 units
#define QSCALE 0.18033688f   // 0.125 * 1.44269504

__device__ __forceinline__ void gld16(const void* g, void* l) {
  __builtin_amdgcn_global_load_lds((const __attribute__((address_space(1))) void*)g,
                                   (__attribute__((address_space(3))) void*)l,
                                   16, 0, 0);
}

__device__ __forceinline__ float fexp2(float x) {
#if __has_builtin(__builtin_amdgcn_exp2f)
  return __builtin_amdgcn_exp2f(x);
#else
  float r; asm("v_exp_f32 %0, %1" : "=v"(r) : "v"(x)); return r;
#endif
}

__device__ __forceinline__ unsigned cvt2(float a, float b) {
  __hip_bfloat162 h = __float22bfloat162_rn(float2{a, b});
  return *reinterpret_cast<unsigned*>(&h);
}

// 4 "byte!=0" flags of a u32, as a nibble (bit j = byte j nonzero)
__device__ __forceinline__ unsigned nib4(unsigned x) {
  const unsigned b = ((x & 0x7F7F7F7Fu) + 0x7F7F7F7Fu) | x;  // bit7 per byte = nonzero
  return ((b >> 7) & 1u) | ((b >> 14) & 2u) | ((b >> 21) & 4u) | ((b >> 28) & 8u);
}

// ---- prep: blocks [0,512) pack mask bits (thread-per-u64-word, ballot-free);
//            blocks [512,1792) convert f32 -> bf16.
__global__ __launch_bounds__(256)
void prep(const unsigned char* __restrict__ mbytes,
          const float* __restrict__ x,  const float* __restrict__ wq,
          const float* __restrict__ wk, const float* __restrict__ wv,
          const float* __restrict__ wo,
          u64* __restrict__ packed,
          uint2* __restrict__ xb,  uint2* __restrict__ wqb,
          uint2* __restrict__ wkb, uint2* __restrict__ wvb,
          uint2* __restrict__ wob)
{
  if (blockIdx.x < 512) {
    // dtype autodetect on the first 4096 bytes (1-byte bool vs int32 layout)
    __shared__ int found;
    if (threadIdx.x == 0) found = 0;
    __syncthreads();
    int loc = 0;
    for (int i = threadIdx.x; i < 4096; i += 256)
      if ((i & 3) && mbytes[i] == 1) loc = 1;
    if (loc) atomicOr(&found, 1);
    __syncthreads();
    const bool bytem = (found != 0);

    const int widx = blockIdx.x * 256 + threadIdx.x;   // one u64 word per thread
    u64 bits = 0;
    if (bytem) {
      const uint4* src = (const uint4*)(mbytes + (size_t)widx * 64);
#pragma unroll
      for (int i = 0; i < 4; ++i) {
        const uint4 v = src[i];
        bits |= (u64)nib4(v.x) << (16 * i + 0);
        bits |= (u64)nib4(v.y) << (16 * i + 4);
        bits |= (u64)nib4(v.z) << (16 * i + 8);
        bits |= (u64)nib4(v.w) << (16 * i + 12);
      }
    } else {
      const uint4* src = (const uint4*)mbytes + (size_t)widx * 16;
#pragma unroll
      for (int i = 0; i < 16; ++i) {
        const uint4 v = src[i];
        const unsigned n = (v.x != 0 ? 1u : 0u) | (v.y != 0 ? 2u : 0u) |
                           (v.z != 0 ? 4u : 0u) | (v.w != 0 ? 8u : 0u);
        bits |= (u64)n << (4 * i);
      }
    }
    packed[widx] = bits;
    return;
  }
  // ---- conversion part ----
  const long XG = (long)Mc * Ec / 4;   // float4 groups
  const long WG = (long)Ec * Ec / 4;
  const long total = XG + 4 * WG;
  const long nthr = (long)(gridDim.x - 512) * 256;
  for (long g = (long)(blockIdx.x - 512) * 256 + threadIdx.x; g < total; g += nthr) {
    const float* src; uint2* dst; long r;
    if (g < XG)              { src = x;  dst = xb;  r = g; }
    else if (g < XG + WG)    { src = wq; dst = wqb; r = g - XG; }
    else if (g < XG + 2*WG)  { src = wk; dst = wkb; r = g - XG - WG; }
    else if (g < XG + 3*WG)  { src = wv; dst = wvb; r = g - XG - 2*WG; }
    else                     { src = wo; dst = wob; r = g - XG - 3*WG; }
    float4 v = reinterpret_cast<const float4*>(src)[r];
    uint2 o;
    o.x = cvt2(v.x, v.y);
    o.y = cvt2(v.z, v.w);
    dst[r] = o;
  }
}

// ---- fused Q/K/V projection, shared A-staging: grid 512 = 32 (bm) x 16 (bn) ----
__global__ __launch_bounds__(256)
void gemm_qkv(const bf16* __restrict__ xb,
              const bf16* __restrict__ wq, const bf16* __restrict__ wk,
              const bf16* __restrict__ wv,
              const float* __restrict__ bq, const float* __restrict__ bk,
              const float* __restrict__ bv,
              bf16* __restrict__ Q, bf16* __restrict__ Ko, bf16* __restrict__ VT)
{
  __shared__ bf16 As[2][128 * 64];      // 32 KB
  __shared__ bf16 Bs[2][3][64 * 64];    // 48 KB
  const int bm = blockIdx.x >> 4, bn = blockIdx.x & 15;
  const int t = threadIdx.x, lane = t & 63, w = t >> 6;
  const int wr = w >> 1, wc = w & 1;
  const int llo = lane & 15, lhi = lane >> 4;
  const int srow = t >> 3, schunk = t & 7;
  const int sswz = schunk ^ (srow & 7);
  const bf16* aSrc  = xb + (size_t)(bm * 128 + srow) * Kc + sswz * 8;
  const bf16* bSrc0 = wq + (size_t)(bn * 64 + srow) * Kc + sswz * 8;
  const bf16* bSrc1 = wk + (size_t)(bn * 64 + srow) * Kc + sswz * 8;
  const bf16* bSrc2 = wv + (size_t)(bn * 64 + srow) * Kc + sswz * 8;

  f32x4 acc[3][4][2] = {};

  auto stage = [&](int buf, int kt) {
    char* ldsA = (char*)As[buf] + w * 1024;
#pragma unroll
    for (int i = 0; i < 4; ++i)
      gld16(aSrc + (size_t)i * 32 * Kc + kt, ldsA + i * 4096);
#pragma unroll
    for (int s = 0; s < 3; ++s) {
      const bf16* bs = s == 0 ? bSrc0 : (s == 1 ? bSrc1 : bSrc2);
      char* ldsB = (char*)Bs[buf][s] + w * 1024;
      gld16(bs + kt, ldsB);
      gld16(bs + (size_t)32 * Kc + kt, ldsB + 4096);
    }
  };

  stage(0, 0);
  __syncthreads();

  for (int kti = 0; kti < Kc / 64; ++kti) {
    const int cur = kti & 1;
    if (kti + 1 < Kc / 64) stage(cur ^ 1, (kti + 1) * 64);
    const char* Asc = (const char*)As[cur];
#pragma unroll
    for (int kk = 0; kk < 2; ++kk) {
      const int chunk = (kk * 4 + lhi) ^ (lane & 7);
      short8 af[4];
#pragma unroll
      for (int i = 0; i < 4; ++i) {
        const int rowa = wr * 64 + i * 16 + llo;
        af[i] = *(const short8*)(Asc + rowa * 128 + chunk * 16);
      }
#pragma unroll
      for (int s = 0; s < 3; ++s) {
        const char* Bsc = (const char*)Bs[cur][s];
        const int rowb0 = wc * 32 + llo;
        short8 bg0 = *(const short8*)(Bsc + rowb0 * 128 + chunk * 16);
        short8 bg1 = *(const short8*)(Bsc + (rowb0 + 16) * 128 + chunk * 16);
#pragma unroll
        for (int i = 0; i < 4; ++i) {
          acc[s][i][0] = MFMA16(af[i], bg0, acc[s][i][0], 0, 0, 0);
          acc[s][i][1] = MFMA16(af[i], bg1, acc[s][i][1], 0, 0, 0);
        }
      }
    }
    __syncthreads();
  }

  // epilogue: write Q (scaled), K, V^T
#pragma unroll
  for (int s = 0; s < 3; ++s) {
    const float* bias = s == 0 ? bq : (s == 1 ? bk : bv);
#pragma unroll
    for (int i = 0; i < 4; ++i)
#pragma unroll
      for (int j = 0; j < 2; ++j)
#pragma unroll
        for (int r = 0; r < 4; ++r) {
          const int m = bm * 128 + wr * 64 + i * 16 + lhi * 4 + r;  // token
          const int e = bn * 64 + wc * 32 + j * 16 + llo;           // embed col
          float v = acc[s][i][j][r] + bias[e];
          if (s == 0) {
            Q[(size_t)m * Ec + e] = __float2bfloat16(v * QSCALE);
          } else if (s == 1) {
            Ko[(size_t)m * Ec + e] = __float2bfloat16(v);
          } else {
            const int b = m >> 11, n = m & 2047, h = e >> 6, d = e & 63;
            VT[(((size_t)(b * Hc + h)) * Dc + d) * Nc + n] = __float2bfloat16(v);
          }
        }
  }
}

// ---- output projection: BM=64 x BN=64, grid 1024 = 64 (bm) x 16 (bn) ----
__global__ __launch_bounds__(256)
void gemm_out(const bf16* __restrict__ ob, const bf16* __restrict__ wo,
              const float* __restrict__ bo, float* __restrict__ out)
{
  __shared__ bf16 As[2][64 * 64], Bs[2][64 * 64];   // 32 KB
  const int bm = blockIdx.x >> 4, bn = blockIdx.x & 15;
  const int t = threadIdx.x, lane = t & 63, w = t >> 6;
  const int wr = w >> 1, wc = w & 1;
  const int llo = lane & 15, lhi = lane >> 4;
  const int srow = t >> 3, schunk = t & 7;
  const int sswz = schunk ^ (srow & 7);            // (srow+32)&7 == srow&7
  const bf16* aSrc = ob + (size_t)(bm * 64 + srow) * Kc + sswz * 8;
  const bf16* bSrc = wo + (size_t)(bn * 64 + srow) * Kc + sswz * 8;

  f32x4 acc[2][2] = {};

  auto stage = [&](int buf, int kt) {
    gld16(aSrc + kt,                     (char*)As[buf] + w * 1024);
    gld16(aSrc + (size_t)32 * Kc + kt,   (char*)As[buf] + 4096 + w * 1024);
    gld16(bSrc + kt,                     (char*)Bs[buf] + w * 1024);
    gld16(bSrc + (size_t)32 * Kc + kt,   (char*)Bs[buf] + 4096 + w * 1024);
  };

  stage(0, 0);
  __syncthreads();

  for (int kti = 0; kti < Kc / 64; ++kti) {
    const int cur = kti & 1;
    if (kti + 1 < Kc / 64) stage(cur ^ 1, (kti + 1) * 64);
    const char* Asc = (const char*)As[cur];
    const char* Bsc = (const char*)Bs[cur];
#pragma unroll
    for (int kk = 0; kk < 2; ++kk) {
      const int chunk = (kk * 4 + lhi) ^ (lane & 7);
      short8 af[2], bg[2];
#pragma unroll
      for (int i = 0; i < 2; ++i) {
        const int rowa = wr * 32 + i * 16 + llo;
        af[i] = *(const short8*)(Asc + rowa * 128 + chunk * 16);
      }
#pragma unroll
      for (int j = 0; j < 2; ++j) {
        const int rowb = wc * 32 + j * 16 + llo;
        bg[j] = *(const short8*)(Bsc + rowb * 128 + chunk * 16);
      }
#pragma unroll
      for (int i = 0; i < 2; ++i)
#pragma unroll
        for (int j = 0; j < 2; ++j)
          acc[i][j] = MFMA16(af[i], bg[j], acc[i][j], 0, 0, 0);
    }
    __syncthreads();
  }

#pragma unroll
  for (int i = 0; i < 2; ++i)
#pragma unroll
    for (int j = 0; j < 2; ++j)
#pragma unroll
      for (int r = 0; r < 4; ++r) {
        const int m = bm * 64 + wr * 32 + i * 16 + lhi * 4 + r;
        const int e = bn * 64 + wc * 32 + j * 16 + llo;
        out[(size_t)m * Ec + e] = acc[i][j][r] + bo[e];
      }
}

// ---- flash attention v12: V served from L2 (registers), not LDS ----
// XCD-local decode keeps each (b,h)'s V L2-resident; V fragments are loaded
// per tile directly global->reg (8 x dwordx4, issued at iteration start so
// QK^T covers the L2 latency). LDS traffic/wave-tile drops 240->144 cyc.
// Cross-tile P pipeline kept: QK(t)->P slot t&1; PV(t-1) from slot (t-1)&1.
__global__ __launch_bounds__(512, 4)
void flash_attn(const bf16* __restrict__ Q, const bf16* __restrict__ Kb,
                const bf16* __restrict__ VT, const u64* __restrict__ mpack,
                bf16* __restrict__ O)
{
  __shared__ bf16 Ks[2][64 * 64];      // [k=64][d=64] swizzled, double-buffered
  __shared__ bf16 Ps[8][2][16 * 64];   // per-wave P, double-buffered (32 KB)
  constexpr int NT = Nc / 64;          // 32 KV tiles
  const int t = threadIdx.x, lane = t & 63, w = t >> 6;      // w in 0..7
  const int bh = blockIdx.x & 31, qt = blockIdx.x >> 5;      // XCD-local decode
  const int b = bh >> 4, h = bh & 15;
  const int q0 = qt * 128 + w * 16;
  const int llo = lane & 15, lhi = lane >> 4;
  const int swz = (lane & 7) << 4;     // == (llo&7)<<4

  // Q B-fragment (col=q=llo, d=lhi*8+j); Q pre-scaled by 0.125*log2e
  short8 aq0, aq1;
  {
    const bf16* qb = Q + ((size_t)(b * Nc + q0 + llo)) * Ec + h * Dc + lhi * 8;
    aq0 = *(const short8*)qb;
    aq1 = *(const short8*)(qb + 32);
  }

  const short8 kOnes = {16256,16256,16256,16256,16256,16256,16256,16256}; // bf16 1.0
  const f32x4 fz = {};
  f32x4 oacc[4] = {};
  f32x4 lacc = {};             // lacc[r] = row-sum l for q = q0+lhi*4+r

  // K staging: 512 threads cover the full 64-row K tile
  const int srow = t >> 3, schunk = t & 7;       // srow 0..63
  const int sswz = schunk ^ (srow & 7);
  const bf16* kSrc = Kb + ((size_t)(b * Nc + srow)) * Ec + h * Dc + sswz * 8;

  // V direct-from-global base: lane (llo,lhi) reads rows d = df*16+llo
  const bf16* vBase = VT + ((size_t)bh * Dc + llo) * Nc + lhi * 8;

  // packed-mask row for this lane's q-row (32 words per row)
  const u64* mrow = mpack + ((size_t)(b * Nc) + q0 + llo) * (Nc / 64);

  auto stageK = [&](int buf, int kt) {
    gld16(kSrc + (size_t)kt * Ec, (char*)Ks[buf] + w * 1024);
  };

  short8 vf[8];   // V fragments for the PV tile (32 VGPRs)
  auto vload = [&](int kt) {
#pragma unroll
    for (int df = 0; df < 4; ++df) {
      const bf16* vp = vBase + (size_t)(df * 16) * Nc + kt;
      vf[df * 2 + 0] = *(const short8*)vp;
      vf[df * 2 + 1] = *(const short8*)(vp + 32);
    }
  };

  char* pw0 = (char*)Ps[w][0] + llo * 128;
  char* pw1 = (char*)Ps[w][1] + llo * 128;

  // QK^T + exp + P-write for the tile resident in KsC; write to pwW
  auto qk_part = [&](const char* KsC, char* pwW, u64 mw) {
    f32x4 s[4];
    __builtin_amdgcn_s_setprio(1);
#pragma unroll
    for (int f = 0; f < 4; ++f) {
      const int row = f * 16 + llo;   // k row in Ks
      short8 kb0 = *(const short8*)(KsC + row * 128 + (((0 + lhi) * 16) ^ swz));
      short8 kb1 = *(const short8*)(KsC + row * 128 + (((4 + lhi) * 16) ^ swz));
      s[f] = MFMA16(kb0, aq0, fz, 0, 0, 0);     // A=K chunk, B=Q, C=0
      s[f] = MFMA16(kb1, aq1, s[f], 0, 0, 0);
    }
    __builtin_amdgcn_s_setprio(0);

    const unsigned mlo = (unsigned)(mw >> (lhi * 4));
    const unsigned mhi = (unsigned)(mw >> (lhi * 4 + 32));
#pragma unroll
    for (int f = 0; f < 4; ++f) {
      const unsigned mf = (f < 2 ? (mlo >> (f * 16)) : (mhi >> ((f - 2) * 16)));
#pragma unroll
      for (int r = 0; r < 4; ++r) {
        const float p = fexp2(s[f][r]);
        s[f][r] = ((mf >> r) & 1u) ? 0.f : p;
      }
    }

#pragma unroll
    for (int f = 0; f < 4; ++f) {
      uint2 pk;
      pk.x = cvt2(s[f][0], s[f][1]);
      pk.y = cvt2(s[f][2], s[f][3]);
      *(uint2*)(pwW + ((f * 32 + lhi * 8) ^ swz)) = pk;
    }
  };

  // PV for the previous tile: P from pwR (drained last barrier), V from vf regs
  auto pv_part = [&](const char* pwR) {
    short8 pa0 = *(const short8*)(pwR + ((0 * 64 + lhi * 16) ^ swz));
    short8 pa1 = *(const short8*)(pwR + ((1 * 64 + lhi * 16) ^ swz));
    __builtin_amdgcn_s_setprio(1);
#pragma unroll
    for (int df = 0; df < 4; ++df) {
      oacc[df] = MFMA16(pa0, vf[df * 2 + 0], oacc[df], 0, 0, 0);
      oacc[df] = MFMA16(pa1, vf[df * 2 + 1], oacc[df], 0, 0, 0);
    }
    lacc = MFMA16(pa0, kOnes, lacc, 0, 0, 0);
    lacc = MFMA16(pa1, kOnes, lacc, 0, 0, 0);
    __builtin_amdgcn_s_setprio(0);
  };

  // prologue: K(0)
  stageK(0, 0);
  __syncthreads();

  // t = 0: QK only; stage K(1)
  stageK(1, 64);
  qk_part((const char*)Ks[0], pw0, mrow[0]);
  __syncthreads();

  // pairs t = (ti, ti+1), ti odd: covers t = 1..NT-2
  for (int ti = 1; ti + 1 < NT; ti += 2) {
    // t = ti (odd): QK from Ks[1]->pw1; PV(ti-1) from pw0 + V(ti-1) regs
    vload((ti - 1) * 64);                 // issue early; QK covers latency
    stageK(0, (ti + 1) * 64);
    qk_part((const char*)Ks[1], pw1, mrow[ti]);
    pv_part(pw0);
    __syncthreads();
    // t = ti+1 (even): QK from Ks[0]->pw0; PV(ti) from pw1 + V(ti) regs
    vload(ti * 64);
    if (ti + 2 < NT) stageK(1, (ti + 2) * 64);
    qk_part((const char*)Ks[0], pw0, mrow[ti + 1]);
    pv_part(pw1);
    __syncthreads();
  }

  // t = NT-1 (odd): QK from Ks[1]->pw1; PV(NT-2) from pw0
  vload((NT - 2) * 64);
  qk_part((const char*)Ks[1], pw1, mrow[NT - 1]);
  pv_part(pw0);
  __syncthreads();

  // drain: PV(NT-1)
  vload((NT - 1) * 64);
  pv_part(pw1);

  // epilogue: O = oacc / l, bf16 (B,N,E); oacc[df][r] = O[q=lhi*4+r][d=df*16+llo]
  float inv[4];
#pragma unroll
  for (int r = 0; r < 4; ++r) inv[r] = 1.0f / lacc[r];
#pragma unroll
  for (int df = 0; df < 4; ++df)
#pragma unroll
    for (int r = 0; r < 4; ++r) {
      const int q = q0 + lhi * 4 + r;
      const int e = h * Dc + df * 16 + llo;
      O[((size_t)(b * Nc + q)) * Ec + e] = __float2bfloat16(oacc[df][r] * inv[r]);
    }
}

extern "C" void kernel_launch(void* const* d_in, const int* in_sizes, int n_in,
                              void* d_out, int out_size, void* d_ws, size_t ws_size,
                              hipStream_t stream)
{
  (void)in_sizes; (void)n_in; (void)out_size; (void)ws_size;
  const float* x  = (const float*)d_in[0];
  // d_in[1] region_mask: unused (softmax shift-invariance)
  const void* mask = d_in[2];
  const float* Wq = (const float*)d_in[3];
  const float* bq = (const float*)d_in[4];
  const float* Wk = (const float*)d_in[5];
  const float* bk = (const float*)d_in[6];
  const float* Wv = (const float*)d_in[7];
  const float* bv = (const float*)d_in[8];
  const float* Wo = (const float*)d_in[9];
  const float* bo = (const float*)d_in[10];
  // d_in[11] region_bias: unused (softmax shift-invariance)
  float* out = (float*)d_out;
  char* ws = (char*)d_ws;

  bf16* XB  = (bf16*)(ws + OFF_XB);
  bf16* WQB = (bf16*)(ws + OFF_WQB);
  bf16* WKB = (bf16*)(ws + OFF_WKB);
  bf16* WVB = (bf16*)(ws + OFF_WVB);
  bf16* WOB = (bf16*)(ws + OFF_WOB);
  bf16* QB  = (bf16*)(ws + OFF_QB);
  bf16* KB  = (bf16*)(ws + OFF_KB);
  bf16* VTB = (bf16*)(ws + OFF_VTB);
  bf16* OB  = (bf16*)(ws + OFF_OB);
  u64*  MP  = (u64*)(ws + OFF_MP);

  prep<<<512 + 1280, 256, 0, stream>>>((const unsigned char*)mask,
                                       x, Wq, Wk, Wv, Wo, MP,
                                       (uint2*)XB, (uint2*)WQB, (uint2*)WKB,
                                       (uint2*)WVB, (uint2*)WOB);
  gemm_qkv<<<512, 256, 0, stream>>>(XB, WQB, WKB, WVB, bq, bk, bv, QB, KB, VTB);
  flash_attn<<<512, 512, 0, stream>>>(QB, KB, VTB, MP, OB);
  gemm_out<<<1024, 256, 0, stream>>>(OB, WOB, bo, out);
}

// Round 15
// 127.641 us; speedup vs baseline: 1.6802x; 1.6802x over previous
//
#include <hip/hip_runtime.h>
#include <hip/hip_bf16.h>
#include <stdint.h>

typedef __hip_bfloat16 bf16;
typedef unsigned long long u64;
typedef __attribute__((ext_vector_type(4))) float f32x4;
typedef __attribute__((ext_vector_type(8))) short short8;

#define MFMA16 __builtin_amdgcn_mfma_f32_16x16x32_bf16

constexpr int Bc = 2, Nc = 2048, Ec = 1024, Hc = 16, Dc = 64;
constexpr int Mc = Bc * Nc;   // 4096 tokens
constexpr int Kc = Ec;        // 1024 inner dim

// ---- ws layout (bytes) ----
constexpr size_t OFF_XB   = 256;
constexpr size_t SZ_XE    = (size_t)Mc * Ec * 2;   // 8 MB (M x E bf16)
constexpr size_t SZ_W     = (size_t)Ec * Ec * 2;   // 2 MB
constexpr size_t OFF_WQB  = OFF_XB  + SZ_XE;
constexpr size_t OFF_WKB  = OFF_WQB + SZ_W;
constexpr size_t OFF_WVB  = OFF_WKB + SZ_W;
constexpr size_t OFF_WOB  = OFF_WVB + SZ_W;
constexpr size_t OFF_QB   = OFF_WOB + SZ_W;
constexpr size_t OFF_KB   = OFF_QB  + SZ_XE;
constexpr size_t OFF_VTB  = OFF_KB  + SZ_XE;       // V transposed (B,H,D,N)
constexpr size_t OFF_OB   = OFF_VTB + SZ_XE;
constexpr size_t OFF_MP   = OFF_OB  + SZ_XE;       // packed mask: 131072 u64 = 1 MB

// Q prescale: 1/sqrt(D) folded with log2(e) so scores are already in exp2 units
#define QSCALE 0.18033688f   // 0.125 * 1.44269504

__device__ __forceinline__ void gld16(const void* g, void* l) {
  __builtin_amdgcn_global_load_lds((const __attribute__((address_space(1))) void*)g,
                                   (__attribute__((address_space(3))) void*)l,
                                   16, 0, 0);
}

__device__ __forceinline__ float fexp2(float x) {
#if __has_builtin(__builtin_amdgcn_exp2f)
  return __builtin_amdgcn_exp2f(x);
#else
  float r; asm("v_exp_f32 %0, %1" : "=v"(r) : "v"(x)); return r;
#endif
}

__device__ __forceinline__ unsigned cvt2(float a, float b) {
  __hip_bfloat162 h = __float22bfloat162_rn(float2{a, b});
  return *reinterpret_cast<unsigned*>(&h);
}

// 4 "byte!=0" flags of a u32, as a nibble (bit j = byte j nonzero)
__device__ __forceinline__ unsigned nib4(unsigned x) {
  const unsigned b = ((x & 0x7F7F7F7Fu) + 0x7F7F7F7Fu) | x;  // bit7 per byte = nonzero
  return ((b >> 7) & 1u) | ((b >> 14) & 2u) | ((b >> 21) & 4u) | ((b >> 28) & 8u);
}

// ---- prep: blocks [0,512) pack mask bits (thread-per-u64-word, ballot-free);
//            blocks [512,1792) convert f32 -> bf16.
__global__ __launch_bounds__(256)
void prep(const unsigned char* __restrict__ mbytes,
          const float* __restrict__ x,  const float* __restrict__ wq,
          const float* __restrict__ wk, const float* __restrict__ wv,
          const float* __restrict__ wo,
          u64* __restrict__ packed,
          uint2* __restrict__ xb,  uint2* __restrict__ wqb,
          uint2* __restrict__ wkb, uint2* __restrict__ wvb,
          uint2* __restrict__ wob)
{
  if (blockIdx.x < 512) {
    // dtype autodetect on the first 4096 bytes (1-byte bool vs int32 layout)
    __shared__ int found;
    if (threadIdx.x == 0) found = 0;
    __syncthreads();
    int loc = 0;
    for (int i = threadIdx.x; i < 4096; i += 256)
      if ((i & 3) && mbytes[i] == 1) loc = 1;
    if (loc) atomicOr(&found, 1);
    __syncthreads();
    const bool bytem = (found != 0);

    const int widx = blockIdx.x * 256 + threadIdx.x;   // one u64 word per thread
    u64 bits = 0;
    if (bytem) {
      const uint4* src = (const uint4*)(mbytes + (size_t)widx * 64);
#pragma unroll
      for (int i = 0; i < 4; ++i) {
        const uint4 v = src[i];
        bits |= (u64)nib4(v.x) << (16 * i + 0);
        bits |= (u64)nib4(v.y) << (16 * i + 4);
        bits |= (u64)nib4(v.z) << (16 * i + 8);
        bits |= (u64)nib4(v.w) << (16 * i + 12);
      }
    } else {
      const uint4* src = (const uint4*)mbytes + (size_t)widx * 16;
#pragma unroll
      for (int i = 0; i < 16; ++i) {
        const uint4 v = src[i];
        const unsigned n = (v.x != 0 ? 1u : 0u) | (v.y != 0 ? 2u : 0u) |
                           (v.z != 0 ? 4u : 0u) | (v.w != 0 ? 8u : 0u);
        bits |= (u64)n << (4 * i);
      }
    }
    packed[widx] = bits;
    return;
  }
  // ---- conversion part ----
  const long XG = (long)Mc * Ec / 4;   // float4 groups
  const long WG = (long)Ec * Ec / 4;
  const long total = XG + 4 * WG;
  const long nthr = (long)(gridDim.x - 512) * 256;
  for (long g = (long)(blockIdx.x - 512) * 256 + threadIdx.x; g < total; g += nthr) {
    const float* src; uint2* dst; long r;
    if (g < XG)              { src = x;  dst = xb;  r = g; }
    else if (g < XG + WG)    { src = wq; dst = wqb; r = g - XG; }
    else if (g < XG + 2*WG)  { src = wk; dst = wkb; r = g - XG - WG; }
    else if (g < XG + 3*WG)  { src = wv; dst = wvb; r = g - XG - 2*WG; }
    else                     { src = wo; dst = wob; r = g - XG - 3*WG; }
    float4 v = reinterpret_cast<const float4*>(src)[r];
    uint2 o;
    o.x = cvt2(v.x, v.y);
    o.y = cvt2(v.z, v.w);
    dst[r] = o;
  }
}

// ---- fused Q/K/V projection, shared A-staging: grid 512 = 32 (bm) x 16 (bn) ----
// Each block computes the SAME 128x64 output tile for all three projections:
// A (x-tile) staged once, three B-tiles (wq/wk/wv). Per kk: 4 A + 6 B LDS reads
// feed 24 MFMAs (0.42 KB/MFMA vs 0.75 in the unfused core). LDS 80 KB -> 2 blk/CU.
__global__ __launch_bounds__(256)
void gemm_qkv(const bf16* __restrict__ xb,
              const bf16* __restrict__ wq, const bf16* __restrict__ wk,
              const bf16* __restrict__ wv,
              const float* __restrict__ bq, const float* __restrict__ bk,
              const float* __restrict__ bv,
              bf16* __restrict__ Q, bf16* __restrict__ Ko, bf16* __restrict__ VT)
{
  __shared__ bf16 As[2][128 * 64];      // 32 KB
  __shared__ bf16 Bs[2][3][64 * 64];    // 48 KB
  const int bm = blockIdx.x >> 4, bn = blockIdx.x & 15;
  const int t = threadIdx.x, lane = t & 63, w = t >> 6;
  const int wr = w >> 1, wc = w & 1;
  const int llo = lane & 15, lhi = lane >> 4;
  const int srow = t >> 3, schunk = t & 7;
  const int sswz = schunk ^ (srow & 7);
  const bf16* aSrc  = xb + (size_t)(bm * 128 + srow) * Kc + sswz * 8;
  const bf16* bSrc0 = wq + (size_t)(bn * 64 + srow) * Kc + sswz * 8;
  const bf16* bSrc1 = wk + (size_t)(bn * 64 + srow) * Kc + sswz * 8;
  const bf16* bSrc2 = wv + (size_t)(bn * 64 + srow) * Kc + sswz * 8;

  f32x4 acc[3][4][2] = {};

  auto stage = [&](int buf, int kt) {
    char* ldsA = (char*)As[buf] + w * 1024;
#pragma unroll
    for (int i = 0; i < 4; ++i)
      gld16(aSrc + (size_t)i * 32 * Kc + kt, ldsA + i * 4096);
#pragma unroll
    for (int s = 0; s < 3; ++s) {
      const bf16* bs = s == 0 ? bSrc0 : (s == 1 ? bSrc1 : bSrc2);
      char* ldsB = (char*)Bs[buf][s] + w * 1024;
      gld16(bs + kt, ldsB);
      gld16(bs + (size_t)32 * Kc + kt, ldsB + 4096);
    }
  };

  stage(0, 0);
  __syncthreads();

  for (int kti = 0; kti < Kc / 64; ++kti) {
    const int cur = kti & 1;
    if (kti + 1 < Kc / 64) stage(cur ^ 1, (kti + 1) * 64);
    const char* Asc = (const char*)As[cur];
#pragma unroll
    for (int kk = 0; kk < 2; ++kk) {
      const int chunk = (kk * 4 + lhi) ^ (lane & 7);
      short8 af[4];
#pragma unroll
      for (int i = 0; i < 4; ++i) {
        const int rowa = wr * 64 + i * 16 + llo;
        af[i] = *(const short8*)(Asc + rowa * 128 + chunk * 16);
      }
#pragma unroll
      for (int s = 0; s < 3; ++s) {
        const char* Bsc = (const char*)Bs[cur][s];
        const int rowb0 = wc * 32 + llo;
        short8 bg0 = *(const short8*)(Bsc + rowb0 * 128 + chunk * 16);
        short8 bg1 = *(const short8*)(Bsc + (rowb0 + 16) * 128 + chunk * 16);
#pragma unroll
        for (int i = 0; i < 4; ++i) {
          acc[s][i][0] = MFMA16(af[i], bg0, acc[s][i][0], 0, 0, 0);
          acc[s][i][1] = MFMA16(af[i], bg1, acc[s][i][1], 0, 0, 0);
        }
      }
    }
    __syncthreads();
  }

  // epilogue: write Q (scaled), K, V^T
#pragma unroll
  for (int s = 0; s < 3; ++s) {
    const float* bias = s == 0 ? bq : (s == 1 ? bk : bv);
#pragma unroll
    for (int i = 0; i < 4; ++i)
#pragma unroll
      for (int j = 0; j < 2; ++j)
#pragma unroll
        for (int r = 0; r < 4; ++r) {
          const int m = bm * 128 + wr * 64 + i * 16 + lhi * 4 + r;  // token
          const int e = bn * 64 + wc * 32 + j * 16 + llo;           // embed col
          float v = acc[s][i][j][r] + bias[e];
          if (s == 0) {
            Q[(size_t)m * Ec + e] = __float2bfloat16(v * QSCALE);
          } else if (s == 1) {
            Ko[(size_t)m * Ec + e] = __float2bfloat16(v);
          } else {
            const int b = m >> 11, n = m & 2047, h = e >> 6, d = e & 63;
            VT[(((size_t)(b * Hc + h)) * Dc + d) * Nc + n] = __float2bfloat16(v);
          }
        }
  }
}

// ---- NT-GEMM core for the output projection (BN=64, double-buffered) ----
template<int BN>
__device__ __forceinline__ void gemm_core(const bf16* __restrict__ A,
                                          const bf16* __restrict__ Bw,
                                          int bm, int bn,
                                          bf16* As0, bf16* As1,
                                          bf16* Bs0, bf16* Bs1,
                                          f32x4 (&acc)[4][BN / 32])
{
  constexpr int NJ = BN / 32;
  const int t = threadIdx.x, lane = t & 63, w = t >> 6;
  const int wr = w >> 1, wc = w & 1;
  const int llo = lane & 15, lhi = lane >> 4;
  const int srow = t >> 3, schunk = t & 7;
  const int sswz = schunk ^ (srow & 7);
  const bf16* aSrc = A  + (size_t)(bm * 128 + srow) * Kc + sswz * 8;
  const bf16* bSrc = Bw + (size_t)(bn * BN  + srow) * Kc + sswz * 8;

  auto stage = [&](bf16* Asb, bf16* Bsb, int kt) {
    char* ldsA = (char*)Asb + w * 1024;
    char* ldsB = (char*)Bsb + w * 1024;
#pragma unroll
    for (int i = 0; i < 4; ++i)
      gld16(aSrc + (size_t)i * 32 * Kc + kt, ldsA + i * 4096);
#pragma unroll
    for (int i = 0; i < BN / 32; ++i)
      gld16(bSrc + (size_t)i * 32 * Kc + kt, ldsB + i * 4096);
  };

  stage(As0, Bs0, 0);
  __syncthreads();

  for (int kti = 0; kti < Kc / 64; ++kti) {
    const bool even = !(kti & 1);
    const char* Asc = (const char*)(even ? As0 : As1);
    const char* Bsc = (const char*)(even ? Bs0 : Bs1);
    if (kti + 1 < Kc / 64)
      stage(even ? As1 : As0, even ? Bs1 : Bs0, (kti + 1) * 64);
#pragma unroll
    for (int kk = 0; kk < 2; ++kk) {
      short8 af[4], bg[NJ];
      const int chunk = (kk * 4 + lhi) ^ (lane & 7);
#pragma unroll
      for (int i = 0; i < 4; ++i) {
        const int rowa = wr * 64 + i * 16 + llo;
        af[i] = *(const short8*)(Asc + rowa * 128 + chunk * 16);
      }
#pragma unroll
      for (int j = 0; j < NJ; ++j) {
        const int rowb = wc * (BN / 2) + j * 16 + llo;
        bg[j] = *(const short8*)(Bsc + rowb * 128 + chunk * 16);
      }
#pragma unroll
      for (int i = 0; i < 4; ++i)
#pragma unroll
        for (int j = 0; j < NJ; ++j)
          acc[i][j] = MFMA16(af[i], bg[j], acc[i][j], 0, 0, 0);
    }
    __syncthreads();
  }
}

// ---- output projection: grid 512 = 32 (bm) x 16 (bn), BN=64, f32 out ----
__global__ __launch_bounds__(256)
void gemm_out(const bf16* __restrict__ ob, const bf16* __restrict__ wo,
              const float* __restrict__ bo, float* __restrict__ out)
{
  __shared__ bf16 As[2][128 * 64], Bs[2][64 * 64];   // 48 KB
  const int bm = blockIdx.x >> 4, bn = blockIdx.x & 15;
  f32x4 acc[4][2] = {};
  gemm_core<64>(ob, wo, bm, bn, As[0], As[1], Bs[0], Bs[1], acc);

  const int t = threadIdx.x, lane = t & 63, w = t >> 6;
  const int wr = w >> 1, wc = w & 1;
  const int llo = lane & 15, lhi = lane >> 4;
#pragma unroll
  for (int i = 0; i < 4; ++i)
#pragma unroll
    for (int j = 0; j < 2; ++j)
#pragma unroll
      for (int r = 0; r < 4; ++r) {
        const int m = bm * 128 + wr * 64 + i * 16 + lhi * 4 + r;
        const int e = bn * 64 + wc * 32 + j * 16 + llo;
        out[(size_t)m * Ec + e] = acc[i][j][r] + bo[e];
      }
}

// ---- flash attention v10: cross-tile P/V pipeline (best measured: 64.7 us) ----
// Iteration t: QK(t)->exp->write P(t) to per-wave slot t&1, and PV(t-1) from
// slot (t-1)&1 + Vs[(t-1)&1] (P-writes drained by the previous barrier -> no
// explicit lgkmcnt(0); PV(t-1) is data-independent of QK(t) so MFMA and exp
// overlap). V staged lag-by-one: stage V(t) during iter t, consume at t+1.
// 8 waves, QBLK=128, grid 512 = (B*H=32) x (N/128=16 q-tiles).
__global__ __launch_bounds__(512, 4)
void flash_attn(const bf16* __restrict__ Q, const bf16* __restrict__ Kb,
                const bf16* __restrict__ VT, const u64* __restrict__ mpack,
                bf16* __restrict__ O)
{
  __shared__ bf16 Ks[2][64 * 64];      // [k=64][d=64] swizzled, double-buffered
  __shared__ bf16 Vs[2][64 * 64];      // [d=64][k=64] swizzled, lag-by-one
  __shared__ bf16 Ps[8][2][16 * 64];   // per-wave P, double-buffered (32 KB)
  constexpr int NT = Nc / 64;          // 32 KV tiles
  const int t = threadIdx.x, lane = t & 63, w = t >> 6;      // w in 0..7
  const int bh = blockIdx.x >> 4, qt = blockIdx.x & 15;
  const int b = bh >> 4, h = bh & 15;
  const int q0 = qt * 128 + w * 16;
  const int llo = lane & 15, lhi = lane >> 4;
  const int swz = (lane & 7) << 4;     // == (llo&7)<<4

  // Q B-fragment (col=q=llo, d=lhi*8+j); Q pre-scaled by 0.125*log2e
  short8 aq0, aq1;
  {
    const bf16* qb = Q + ((size_t)(b * Nc + q0 + llo)) * Ec + h * Dc + lhi * 8;
    aq0 = *(const short8*)qb;
    aq1 = *(const short8*)(qb + 32);
  }

  const short8 kOnes = {16256,16256,16256,16256,16256,16256,16256,16256}; // bf16 1.0
  const f32x4 fz = {};
  f32x4 oacc[4] = {};
  f32x4 lacc = {};             // lacc[r] = row-sum l for q = q0+lhi*4+r

  // staging: 512 threads cover the full 64-row K tile / 64-row V tile
  const int srow = t >> 3, schunk = t & 7;       // srow 0..63
  const int sswz = schunk ^ (srow & 7);
  const bf16* kSrc = Kb + ((size_t)(b * Nc + srow)) * Ec + h * Dc + sswz * 8;
  const bf16* vSrc = VT + ((size_t)(bh * Dc + srow)) * Nc + sswz * 8;

  // packed-mask row for this lane's q-row (32 words per row)
  const u64* mrow = mpack + ((size_t)(b * Nc) + q0 + llo) * (Nc / 64);

  auto stageK = [&](int buf, int kt) {
    gld16(kSrc + (size_t)kt * Ec, (char*)Ks[buf] + w * 1024);
  };
  auto stageV = [&](int buf, int kt) {
    gld16(vSrc + kt, (char*)Vs[buf] + w * 1024);
  };

  char* pw0 = (char*)Ps[w][0] + llo * 128;
  char* pw1 = (char*)Ps[w][1] + llo * 128;

  // QK^T + exp + P-write for the tile resident in KsC; write to pwW
  auto qk_part = [&](const char* KsC, char* pwW, u64 mw) {
    f32x4 s[4];
    __builtin_amdgcn_s_setprio(1);
#pragma unroll
    for (int f = 0; f < 4; ++f) {
      const int row = f * 16 + llo;   // k row in Ks
      short8 kb0 = *(const short8*)(KsC + row * 128 + (((0 + lhi) * 16) ^ swz));
      short8 kb1 = *(const short8*)(KsC + row * 128 + (((4 + lhi) * 16) ^ swz));
      s[f] = MFMA16(kb0, aq0, fz, 0, 0, 0);     // A=K chunk, B=Q, C=0
      s[f] = MFMA16(kb1, aq1, s[f], 0, 0, 0);
    }
    __builtin_amdgcn_s_setprio(0);

    const unsigned mlo = (unsigned)(mw >> (lhi * 4));
    const unsigned mhi = (unsigned)(mw >> (lhi * 4 + 32));
#pragma unroll
    for (int f = 0; f < 4; ++f) {
      const unsigned mf = (f < 2 ? (mlo >> (f * 16)) : (mhi >> ((f - 2) * 16)));
#pragma unroll
      for (int r = 0; r < 4; ++r) {
        const float p = fexp2(s[f][r]);
        s[f][r] = ((mf >> r) & 1u) ? 0.f : p;
      }
    }

#pragma unroll
    for (int f = 0; f < 4; ++f) {
      uint2 pk;
      pk.x = cvt2(s[f][0], s[f][1]);
      pk.y = cvt2(s[f][2], s[f][3]);
      *(uint2*)(pwW + ((f * 32 + lhi * 8) ^ swz)) = pk;
    }
  };

  // PV for the previous tile: P from pwR (drained last barrier), V from VsC
  auto pv_part = [&](const char* pwR, const char* VsC) {
    short8 pa0 = *(const short8*)(pwR + ((0 * 64 + lhi * 16) ^ swz));
    short8 pa1 = *(const short8*)(pwR + ((1 * 64 + lhi * 16) ^ swz));
    __builtin_amdgcn_s_setprio(1);
#pragma unroll
    for (int df = 0; df < 4; ++df) {
      const int row = df * 16 + llo;  // d row in Vs
      short8 vb0 = *(const short8*)(VsC + row * 128 + (((0 + lhi) * 16) ^ swz));
      short8 vb1 = *(const short8*)(VsC + row * 128 + (((4 + lhi) * 16) ^ swz));
      oacc[df] = MFMA16(pa0, vb0, oacc[df], 0, 0, 0);
      oacc[df] = MFMA16(pa1, vb1, oacc[df], 0, 0, 0);
    }
    lacc = MFMA16(pa0, kOnes, lacc, 0, 0, 0);
    lacc = MFMA16(pa1, kOnes, lacc, 0, 0, 0);
    __builtin_amdgcn_s_setprio(0);
  };

  // prologue: K(0)
  stageK(0, 0);
  __syncthreads();

  // t = 0: QK only; stage K(1), V(0)
  stageK(1, 64);
  stageV(0, 0);
  qk_part((const char*)Ks[0], pw0, mrow[0]);
  __syncthreads();

  // pairs t = (ti, ti+1), ti odd: covers t = 1..NT-2
  for (int ti = 1; ti + 1 < NT; ti += 2) {
    // t = ti (odd): Ks[1]->pw1; PV(ti-1) from pw0/Vs[0]
    stageK(0, (ti + 1) * 64);
    stageV(1, ti * 64);
    pv_part(pw0, (const char*)Vs[0]);
    qk_part((const char*)Ks[1], pw1, mrow[ti]);
    __syncthreads();
    // t = ti+1 (even): Ks[0]->pw0; PV(ti) from pw1/Vs[1]
    if (ti + 2 < NT) stageK(1, (ti + 2) * 64);
    stageV(0, (ti + 1) * 64);
    pv_part(pw1, (const char*)Vs[1]);
    qk_part((const char*)Ks[0], pw0, mrow[ti + 1]);
    __syncthreads();
  }

  // t = NT-1 (odd): Ks[1]->pw1; PV(NT-2) from pw0/Vs[0]; stage V(NT-1)
  stageV(1, (NT - 1) * 64);
  pv_part(pw0, (const char*)Vs[0]);
  qk_part((const char*)Ks[1], pw1, mrow[NT - 1]);
  __syncthreads();

  // drain: PV(NT-1)
  pv_part(pw1, (const char*)Vs[1]);

  // epilogue: O = oacc / l, bf16 (B,N,E); oacc[df][r] = O[q=lhi*4+r][d=df*16+llo]
  float inv[4];
#pragma unroll
  for (int r = 0; r < 4; ++r) inv[r] = 1.0f / lacc[r];
#pragma unroll
  for (int df = 0; df < 4; ++df)
#pragma unroll
    for (int r = 0; r < 4; ++r) {
      const int q = q0 + lhi * 4 + r;
      const int e = h * Dc + df * 16 + llo;
      O[((size_t)(b * Nc + q)) * Ec + e] = __float2bfloat16(oacc[df][r] * inv[r]);
    }
}

extern "C" void kernel_launch(void* const* d_in, const int* in_sizes, int n_in,
                              void* d_out, int out_size, void* d_ws, size_t ws_size,
                              hipStream_t stream)
{
  (void)in_sizes; (void)n_in; (void)out_size; (void)ws_size;
  const float* x  = (const float*)d_in[0];
  // d_in[1] region_mask: unused (softmax shift-invariance)
  const void* mask = d_in[2];
  const float* Wq = (const float*)d_in[3];
  const float* bq = (const float*)d_in[4];
  const float* Wk = (const float*)d_in[5];
  const float* bk = (const float*)d_in[6];
  const float* Wv = (const float*)d_in[7];
  const float* bv = (const float*)d_in[8];
  const float* Wo = (const float*)d_in[9];
  const float* bo = (const float*)d_in[10];
  // d_in[11] region_bias: unused (softmax shift-invariance)
  float* out = (float*)d_out;
  char* ws = (char*)d_ws;

  bf16* XB  = (bf16*)(ws + OFF_XB);
  bf16* WQB = (bf16*)(ws + OFF_WQB);
  bf16* WKB = (bf16*)(ws + OFF_WKB);
  bf16* WVB = (bf16*)(ws + OFF_WVB);
  bf16* WOB = (bf16*)(ws + OFF_WOB);
  bf16* QB  = (bf16*)(ws + OFF_QB);
  bf16* KB  = (bf16*)(ws + OFF_KB);
  bf16* VTB = (bf16*)(ws + OFF_VTB);
  bf16* OB  = (bf16*)(ws + OFF_OB);
  u64*  MP  = (u64*)(ws + OFF_MP);

  prep<<<512 + 1280, 256, 0, stream>>>((const unsigned char*)mask,
                                       x, Wq, Wk, Wv, Wo, MP,
                                       (uint2*)XB, (uint2*)WQB, (uint2*)WKB,
                                       (uint2*)WVB, (uint2*)WOB);
  gemm_qkv<<<512, 256, 0, stream>>>(XB, WQB, WKB, WVB, bq, bk, bv, QB, KB, VTB);
  flash_attn<<<512, 512, 0, stream>>>(QB, KB, VTB, MP, OB);
  gemm_out<<<512, 256, 0, stream>>>(OB, WOB, bo, out);
}